// Round 3
// baseline (152.030 us; speedup 1.0000x reference)
//
#include <hip/hip_runtime.h>

// YOLOv1 loss: N=8192, S=7, C=30 -> 401408 cells, 96.4 MB read, scalar out.
// Coalesced global_load_lds staging (16-B width only), block-level 128-cell
// double-buffered tiles, one __syncthreads per tile, compute spread over all
// 4 waves (lanes 0-31 of each wave own one cell).
//
// *** DIAGNOSTIC BUILD: REPEAT=4 sweeps (traffic x4) so the kernel dispatch
// *** exceeds the ~41 us harness poison-fills and surfaces in rocprof top-5
// *** with real counters. Output is identical (only last pass committed;
// *** early passes kept live via asm barrier, not DCE-able).
// *** Production build: set REPEAT=1.
#define REPEAT 4

#define NCH 30
#define CELLS_PER_SAMPLE 49
#define TILE_CELLS 128
#define ARR_TILE_BYTES (TILE_CELLS * NCH * 4)   // 15360
#define TILE_BYTES (2 * ARR_TILE_BYTES)         // 30720
#define NXFER 30                                // 1024-B wave transfers per tile
#define NBLOCKS 512

__device__ __forceinline__ void gl_lds16(const char* g, char* l) {
    __builtin_amdgcn_global_load_lds(
        (const __attribute__((address_space(1))) unsigned int*)g,
        (__attribute__((address_space(3))) unsigned int*)l, 16, 0, 0);
}

// Stage one 30720-B tile (p half then t half, LDS-linear). Wave w issues
// transfers {w, w+4, ...}: waves 0,1 -> 8 transfers, waves 2,3 -> 7.
// All branch conditions are wave-uniform (scalar branches, no divergence).
// LDS dest is wave-uniform base + lane*16 (hardware adds the lane offset).
__device__ __forceinline__ void stage_tile(const char* __restrict__ p,
                                           const char* __restrict__ t,
                                           int tile, char* ldst, int wid, int lane) {
    size_t base = (size_t)tile * ARR_TILE_BYTES + (size_t)lane * 16;
    #pragma unroll
    for (int i = 0; i < 8; ++i) {
        int j = wid + 4 * i;
        if (j < NXFER) {
            const char* src = (j < 15)
                ? p + base + (size_t)j * 1024
                : t + base + (size_t)(j - 15) * 1024;
            gl_lds16(src, ldst + j * 1024);
        }
    }
}

__device__ __forceinline__ float iou_f(float a0, float a1, float a2, float a3,
                                       float b0, float b1, float b2, float b3) {
    float xl = fmaxf(a0, b0);
    float yt = fmaxf(a1, b1);
    float xr = fminf(a2, b2);
    float yb = fminf(a3, b3);
    float ix = fmaxf(xr - xl, 0.0f);
    float iy = fmaxf(yb - yt, 0.0f);
    float inter = ix * iy;
    float aa = fabsf((a2 - a0) * (a3 - a1));
    float ba = fabsf((b2 - b0) * (b3 - b1));
    return inter / (aa + ba - inter + 1e-7f);
}

__device__ __forceinline__ float cell_loss_f(const float* __restrict__ pv,
                                             const float* __restrict__ tv,
                                             int cell) {
    int rem = cell % CELLS_PER_SAMPLE;
    int ci = rem / 7;   // row
    int cj = rem % 7;   // col

    float ltx = (float)cj / 7.0f;
    float lty = (float)ci / 7.0f;

    float coord = (tv[4] > 0.0f) ? 1.0f : 0.0f;
    float noobj = (tv[4] == 0.0f) ? 1.0f : 0.0f;

    // predicted box 1
    float b1x1 = ltx + pv[0] / 7.0f - pv[2] * 0.5f;
    float b1y1 = lty + pv[1] / 7.0f - pv[3] * 0.5f;
    float b1x2 = pv[2] + b1x1;
    float b1y2 = pv[3] + b1y1;

    // predicted box 2 (faithful: p[5:7]*(1/S - 0.5))
    const float C2 = (float)(1.0 / 7.0 - 0.5);
    float b2x1 = ltx + pv[5] * C2;
    float b2y1 = lty + pv[6] * C2;
    float b2x2 = pv[7] + b2x1;
    float b2y2 = pv[8] + b2y1;

    // target box
    float tbx1 = ltx + tv[0] / 7.0f - tv[2] * 0.5f;
    float tby1 = lty + tv[1] / 7.0f - tv[3] * 0.5f;
    float tbx2 = tv[2] + tbx1;
    float tby2 = tv[3] + tby1;

    float iou1 = iou_f(b1x1, b1y1, b1x2, b1y2, tbx1, tby1, tbx2, tby2);
    float iou2 = iou_f(b2x1, b2y1, b2x2, b2y2, tbx1, tby1, tbx2, tby2);

    bool sel = (iou1 >= iou2);
    float bx = sel ? pv[0] : pv[5];
    float by = sel ? pv[1] : pv[6];
    float bw = sel ? pv[2] : pv[7];
    float bh = sel ? pv[3] : pv[8];
    float bc = sel ? pv[4] : pv[9];

    float dx = bx - tv[0];
    float dy = by - tv[1];
    float xy_se = dx * dx + dy * dy;

    float sw = (bw > 0.0f) ? 1.0f : ((bw < 0.0f) ? -1.0f : 0.0f);
    float sh = (bh > 0.0f) ? 1.0f : ((bh < 0.0f) ? -1.0f : 0.0f);
    float dw = sw * sqrtf(fabsf(bw)) - sqrtf(tv[2]);
    float dh = sh * sqrtf(fabsf(bh)) - sqrtf(tv[3]);
    float wh_se = dw * dw + dh * dh;

    float mio = fmaxf(iou1, iou2);
    float dob = mio - bc;
    float obj_se = dob * dob;

    float d4 = pv[4] - tv[4];
    float d9 = pv[9] - tv[9];
    float noobj_se = d4 * d4 + d9 * d9;

    float lab = 0.0f;
    #pragma unroll
    for (int k = 10; k < NCH; ++k) {
        float d = pv[k] - tv[k];
        lab += d * d;
    }

    return coord * (5.0f * (xy_se + wh_se) + obj_se + lab)
         + 0.5f * noobj * noobj_se;
}

__global__ __launch_bounds__(256, 2) void yolo_loss_kernel(
    const char* __restrict__ p, const char* __restrict__ t,
    float* __restrict__ out, int ntiles, float inv_n)
{
    __shared__ char lds[2 * TILE_BYTES];   // 61440 B
    __shared__ float wave_sums[4];

    const int tid  = threadIdx.x;
    const int lane = tid & 63;
    const int wid  = tid >> 6;

    float acc = 0.0f;
    #pragma unroll 1
    for (int pass = 0; pass < REPEAT; ++pass) {
        // pass > 0: make sure every wave is done reading the buffers
        // before the prologue stage overwrites buffer 0.
        __syncthreads();

        float a = 0.0f;
        int tile = blockIdx.x;
        int buf = 0;
        if (tile < ntiles) stage_tile(p, t, tile, lds, wid, lane);

        for (; tile < ntiles; tile += NBLOCKS) {
            int next = tile + NBLOCKS;
            // Drain this tile's staging loads (issued one iteration ago),
            // then barrier: buf is ready AND everyone finished reading buf^1.
            asm volatile("s_waitcnt vmcnt(0)" ::: "memory");
            __syncthreads();
            if (next < ntiles)
                stage_tile(p, t, next, lds + (buf ^ 1) * TILE_BYTES, wid, lane);

            if (lane < 32) {
                int c = (wid << 5) | lane;   // cell within tile, spread over 4 waves
                const float* pvp = (const float*)(lds + buf * TILE_BYTES) + c * NCH;
                const float* tvp = (const float*)(lds + buf * TILE_BYTES + ARR_TILE_BYTES) + c * NCH;

                float pv[NCH], tv[NCH];
                #pragma unroll
                for (int k = 0; k < NCH / 2; ++k) {
                    float2 va = ((const float2*)pvp)[k];
                    float2 vb = ((const float2*)tvp)[k];
                    pv[2 * k] = va.x; pv[2 * k + 1] = va.y;
                    tv[2 * k] = vb.x; tv[2 * k + 1] = vb.y;
                }

                a += cell_loss_f(pv, tv, tile * TILE_CELLS + c);
            }

            buf ^= 1;
            asm volatile("s_waitcnt lgkmcnt(0)" ::: "memory");
        }

        // Keep every pass's compute live (prevents DCE of diagnostic passes);
        // architecturally only the last pass's value survives.
        asm volatile("" : "+v"(a));
        acc = a;
    }

    acc *= inv_n;

    // wave-64 shuffle reduction
    #pragma unroll
    for (int off = 32; off > 0; off >>= 1)
        acc += __shfl_down(acc, off, 64);

    if (lane == 0) wave_sums[wid] = acc;
    __syncthreads();
    if (tid == 0) {
        atomicAdd(out, wave_sums[0] + wave_sums[1] + wave_sums[2] + wave_sums[3]);
    }
}

extern "C" void kernel_launch(void* const* d_in, const int* in_sizes, int n_in,
                              void* d_out, int out_size, void* d_ws, size_t ws_size,
                              hipStream_t stream) {
    const char* p = (const char*)d_in[0];   // modely [N,7,7,30] f32
    const char* t = (const char*)d_in[1];   // targety [N,7,7,30] f32
    float* out = (float*)d_out;

    int ncells = in_sizes[0] / NCH;                  // 401408
    int nsamples = ncells / CELLS_PER_SAMPLE;        // 8192
    int ntiles = ncells / TILE_CELLS;                // 3136 (exact)

    // d_out is poisoned before every timed launch — zero it first.
    hipMemsetAsync(out, 0, sizeof(float) * (size_t)out_size, stream);

    yolo_loss_kernel<<<NBLOCKS, 256, 0, stream>>>(
        p, t, out, ntiles, 1.0f / (float)nsamples);
}

// Round 4
// 115.095 us; speedup vs baseline: 1.3209x; 1.3209x over previous
//
#include <hip/hip_runtime.h>

// YOLOv1 loss: N=8192, S=7, C=30 -> 401408 cells, 96.4 MB read, scalar out.
// Coalesced global_load_lds staging (16-B width only), block-level 128-cell
// double-buffered tiles, one __syncthreads per tile, compute spread over all
// 4 waves (lanes 0-31 of each wave own one cell).
//
// ROOFLINE EVIDENCE (R3 diagnostic, REPEAT=4): 65 us for 4 sweeps
// = 16.25 us/sweep = 5.93 TB/s consumption = 94% of the 6.3 TB/s
// achievable HBM ceiling (theoretical floor 15.3 us). Passes served from
// L3 ran no faster -> the loop consumes at ~5.9 TB/s regardless of source;
// production pass is HBM-limited. This build is the production REPEAT=1.

#define NCH 30
#define CELLS_PER_SAMPLE 49
#define TILE_CELLS 128
#define ARR_TILE_BYTES (TILE_CELLS * NCH * 4)   // 15360
#define TILE_BYTES (2 * ARR_TILE_BYTES)         // 30720
#define NXFER 30                                // 1024-B wave transfers per tile
#define NBLOCKS 512

__device__ __forceinline__ void gl_lds16(const char* g, char* l) {
    __builtin_amdgcn_global_load_lds(
        (const __attribute__((address_space(1))) unsigned int*)g,
        (__attribute__((address_space(3))) unsigned int*)l, 16, 0, 0);
}

// Stage one 30720-B tile (p half then t half, LDS-linear). Wave w issues
// transfers {w, w+4, ...}: waves 0,1 -> 8 transfers, waves 2,3 -> 7.
// All branch conditions are wave-uniform (scalar branches, no divergence).
// LDS dest is wave-uniform base + lane*16 (hardware adds the lane offset).
__device__ __forceinline__ void stage_tile(const char* __restrict__ p,
                                           const char* __restrict__ t,
                                           int tile, char* ldst, int wid, int lane) {
    size_t base = (size_t)tile * ARR_TILE_BYTES + (size_t)lane * 16;
    #pragma unroll
    for (int i = 0; i < 8; ++i) {
        int j = wid + 4 * i;
        if (j < NXFER) {
            const char* src = (j < 15)
                ? p + base + (size_t)j * 1024
                : t + base + (size_t)(j - 15) * 1024;
            gl_lds16(src, ldst + j * 1024);
        }
    }
}

__device__ __forceinline__ float iou_f(float a0, float a1, float a2, float a3,
                                       float b0, float b1, float b2, float b3) {
    float xl = fmaxf(a0, b0);
    float yt = fmaxf(a1, b1);
    float xr = fminf(a2, b2);
    float yb = fminf(a3, b3);
    float ix = fmaxf(xr - xl, 0.0f);
    float iy = fmaxf(yb - yt, 0.0f);
    float inter = ix * iy;
    float aa = fabsf((a2 - a0) * (a3 - a1));
    float ba = fabsf((b2 - b0) * (b3 - b1));
    return inter / (aa + ba - inter + 1e-7f);
}

__device__ __forceinline__ float cell_loss_f(const float* __restrict__ pv,
                                             const float* __restrict__ tv,
                                             int cell) {
    int rem = cell % CELLS_PER_SAMPLE;
    int ci = rem / 7;   // row
    int cj = rem % 7;   // col

    float ltx = (float)cj / 7.0f;
    float lty = (float)ci / 7.0f;

    float coord = (tv[4] > 0.0f) ? 1.0f : 0.0f;
    float noobj = (tv[4] == 0.0f) ? 1.0f : 0.0f;

    // predicted box 1
    float b1x1 = ltx + pv[0] / 7.0f - pv[2] * 0.5f;
    float b1y1 = lty + pv[1] / 7.0f - pv[3] * 0.5f;
    float b1x2 = pv[2] + b1x1;
    float b1y2 = pv[3] + b1y1;

    // predicted box 2 (faithful: p[5:7]*(1/S - 0.5))
    const float C2 = (float)(1.0 / 7.0 - 0.5);
    float b2x1 = ltx + pv[5] * C2;
    float b2y1 = lty + pv[6] * C2;
    float b2x2 = pv[7] + b2x1;
    float b2y2 = pv[8] + b2y1;

    // target box
    float tbx1 = ltx + tv[0] / 7.0f - tv[2] * 0.5f;
    float tby1 = lty + tv[1] / 7.0f - tv[3] * 0.5f;
    float tbx2 = tv[2] + tbx1;
    float tby2 = tv[3] + tby1;

    float iou1 = iou_f(b1x1, b1y1, b1x2, b1y2, tbx1, tby1, tbx2, tby2);
    float iou2 = iou_f(b2x1, b2y1, b2x2, b2y2, tbx1, tby1, tbx2, tby2);

    bool sel = (iou1 >= iou2);
    float bx = sel ? pv[0] : pv[5];
    float by = sel ? pv[1] : pv[6];
    float bw = sel ? pv[2] : pv[7];
    float bh = sel ? pv[3] : pv[8];
    float bc = sel ? pv[4] : pv[9];

    float dx = bx - tv[0];
    float dy = by - tv[1];
    float xy_se = dx * dx + dy * dy;

    float sw = (bw > 0.0f) ? 1.0f : ((bw < 0.0f) ? -1.0f : 0.0f);
    float sh = (bh > 0.0f) ? 1.0f : ((bh < 0.0f) ? -1.0f : 0.0f);
    float dw = sw * sqrtf(fabsf(bw)) - sqrtf(tv[2]);
    float dh = sh * sqrtf(fabsf(bh)) - sqrtf(tv[3]);
    float wh_se = dw * dw + dh * dh;

    float mio = fmaxf(iou1, iou2);
    float dob = mio - bc;
    float obj_se = dob * dob;

    float d4 = pv[4] - tv[4];
    float d9 = pv[9] - tv[9];
    float noobj_se = d4 * d4 + d9 * d9;

    float lab = 0.0f;
    #pragma unroll
    for (int k = 10; k < NCH; ++k) {
        float d = pv[k] - tv[k];
        lab += d * d;
    }

    return coord * (5.0f * (xy_se + wh_se) + obj_se + lab)
         + 0.5f * noobj * noobj_se;
}

__global__ __launch_bounds__(256, 2) void yolo_loss_kernel(
    const char* __restrict__ p, const char* __restrict__ t,
    float* __restrict__ out, int ntiles, float inv_n)
{
    __shared__ char lds[2 * TILE_BYTES];   // 61440 B
    __shared__ float wave_sums[4];

    const int tid  = threadIdx.x;
    const int lane = tid & 63;
    const int wid  = tid >> 6;

    float acc = 0.0f;
    int tile = blockIdx.x;
    int buf = 0;
    if (tile < ntiles) stage_tile(p, t, tile, lds, wid, lane);

    for (; tile < ntiles; tile += NBLOCKS) {
        int next = tile + NBLOCKS;
        // Drain this tile's staging loads (issued one iteration ago),
        // then barrier: buf is ready AND everyone finished reading buf^1.
        asm volatile("s_waitcnt vmcnt(0)" ::: "memory");
        __syncthreads();
        if (next < ntiles)
            stage_tile(p, t, next, lds + (buf ^ 1) * TILE_BYTES, wid, lane);

        if (lane < 32) {
            int c = (wid << 5) | lane;   // cell within tile, spread over 4 waves
            const float* pvp = (const float*)(lds + buf * TILE_BYTES) + c * NCH;
            const float* tvp = (const float*)(lds + buf * TILE_BYTES + ARR_TILE_BYTES) + c * NCH;

            float pv[NCH], tv[NCH];
            #pragma unroll
            for (int k = 0; k < NCH / 2; ++k) {
                float2 va = ((const float2*)pvp)[k];
                float2 vb = ((const float2*)tvp)[k];
                pv[2 * k] = va.x; pv[2 * k + 1] = va.y;
                tv[2 * k] = vb.x; tv[2 * k + 1] = vb.y;
            }

            acc += cell_loss_f(pv, tv, tile * TILE_CELLS + c);
        }

        buf ^= 1;
        // all ds_reads of this buffer must complete before the next
        // iteration's global_load_lds overwrites it.
        asm volatile("s_waitcnt lgkmcnt(0)" ::: "memory");
    }

    acc *= inv_n;

    // wave-64 shuffle reduction
    #pragma unroll
    for (int off = 32; off > 0; off >>= 1)
        acc += __shfl_down(acc, off, 64);

    if (lane == 0) wave_sums[wid] = acc;
    __syncthreads();
    if (tid == 0) {
        atomicAdd(out, wave_sums[0] + wave_sums[1] + wave_sums[2] + wave_sums[3]);
    }
}

extern "C" void kernel_launch(void* const* d_in, const int* in_sizes, int n_in,
                              void* d_out, int out_size, void* d_ws, size_t ws_size,
                              hipStream_t stream) {
    const char* p = (const char*)d_in[0];   // modely [N,7,7,30] f32
    const char* t = (const char*)d_in[1];   // targety [N,7,7,30] f32
    float* out = (float*)d_out;

    int ncells = in_sizes[0] / NCH;                  // 401408
    int nsamples = ncells / CELLS_PER_SAMPLE;        // 8192
    int ntiles = ncells / TILE_CELLS;                // 3136 (exact)

    // d_out is poisoned before every timed launch — zero it first.
    hipMemsetAsync(out, 0, sizeof(float) * (size_t)out_size, stream);

    yolo_loss_kernel<<<NBLOCKS, 256, 0, stream>>>(
        p, t, out, ntiles, 1.0f / (float)nsamples);
}